// Round 14
// baseline (374.604 us; speedup 1.0000x reference)
//
#include <hip/hip_runtime.h>
#include <cstdint>
#include <cstddef>

#define HW 512
#define SPATIAL (HW*HW)              // 262144
#define BATCH 16
#define CH 3
#define NPLANE (BATCH*CH)            // 48
#define NELEM ((size_t)NPLANE*SPATIAL) // 12582912
#define GROWS (NPLANE*HW)            // 24576 global rows
#define K_SELECT 78643
#define NITER 8
#define CAP_TIES 4096
#define NSLOT 64
#define PAD 8     // doubles per slot -> one 64B line per slot
#define RBAND 4   // rows per wave in k_rhs (plane-local)
#define CBAND 6   // global rows per wave in k_cg -> 4096 waves = 1 residency round

typedef _Float16 h16;
typedef __attribute__((ext_vector_type(8))) _Float16 h16x8;  // 16B
typedef __attribute__((ext_vector_type(8))) float f32x8;     // 32B

// workspace layout: 3 rotating p buffers, x, bits, dots, betas/alphas, hists
static const size_t OFF_P0   = 0;                      // h16[NELEM]
static const size_t OFF_P1   = NELEM*2;                // h16[NELEM]
static const size_t OFF_P2   = NELEM*4;                // h16[NELEM]
static const size_t OFF_BITS = NELEM*6;                // uint32[BATCH*8192] = 512KB (fully written)
static const size_t OFF_X    = OFF_BITS + (size_t)BATCH*8192*4;   // h16[NELEM] (written by iter-2 do_x, no memset)
static const size_t OFF_DOTS = OFF_X + NELEM*2;        // double[(NITER+1)*3*NSLOT*PAD]  <- memset starts here
static const size_t OFF_BETA = OFF_DOTS + (size_t)(NITER+1)*3*NSLOT*PAD*8;  // double[NITER+1]
static const size_t OFF_ALPH = OFF_BETA + (size_t)(NITER+1)*8;              // double[NITER+1]
static const size_t OFF_HC   = OFF_ALPH + (size_t)(NITER+1)*8;
static const size_t OFF_HF   = OFF_HC + (size_t)BATCH*1024*4;
static const size_t OFF_SEL  = OFF_HF + (size_t)BATCH*1024*4;     // int[16][4]
static const size_t OFF_TC   = OFF_SEL + (size_t)BATCH*4*4;       // int[16]
static const size_t OFF_TL   = OFF_TC + 64;                       // int[16][CAP_TIES]

// ---------------- mask pipeline ----------------
__global__ __launch_bounds__(256) void k_hist_coarse(const int* __restrict__ smap, int* __restrict__ hist){
  __shared__ int h[1024];
  int tid = threadIdx.x;
  for (int j=tid;j<1024;j+=256) h[j]=0;
  __syncthreads();
  int b = blockIdx.y;
  int base = b*SPATIAL + blockIdx.x*4096;
  #pragma unroll
  for (int e=0;e<16;e++){
    int v = smap[base + e*256 + tid];
    atomicAdd(&h[v>>10], 1);
  }
  __syncthreads();
  for (int j=tid;j<1024;j+=256){ int c=h[j]; if(c) atomicAdd(&hist[b*1024+j], c); }
}

__global__ __launch_bounds__(1024) void k_select_coarse(const int* __restrict__ hist, int* __restrict__ sel){
  int lane = threadIdx.x, b = threadIdx.y;
  const int* h = hist + b*1024;
  int loc[16]; int s=0;
  #pragma unroll
  for (int j=0;j<16;j++){ loc[j]=h[lane*16+j]; s+=loc[j]; }
  int T=s;
  #pragma unroll
  for (int o=1;o<64;o<<=1){ int t=__shfl_down(T,o,64); if (lane+o<64) T+=t; }
  int S = T - s;
  if (S < K_SELECT && T >= K_SELECT){
    int acc=S;
    #pragma unroll
    for (int j=15;j>=0;j--){
      acc+=loc[j];
      if (acc>=K_SELECT){ sel[b*4+0]=lane*16+j; sel[b*4+1]=acc-loc[j]; break; }
    }
  }
}

__global__ __launch_bounds__(256) void k_hist_fine(const int* __restrict__ smap, const int* __restrict__ sel, int* __restrict__ hist){
  __shared__ int h[1024];
  int tid=threadIdx.x;
  for (int j=tid;j<1024;j+=256) h[j]=0;
  __syncthreads();
  int b=blockIdx.y;
  int cb = sel[b*4+0];
  int base = b*SPATIAL + blockIdx.x*4096;
  #pragma unroll
  for (int e=0;e<16;e++){
    int v = smap[base+e*256+tid];
    if ((v>>10)==cb) atomicAdd(&h[v&1023],1);
  }
  __syncthreads();
  for (int j=tid;j<1024;j+=256){ int c=h[j]; if(c) atomicAdd(&hist[b*1024+j],c); }
}

__global__ __launch_bounds__(1024) void k_select_fine(const int* __restrict__ hist, int* __restrict__ sel){
  int lane = threadIdx.x, b = threadIdx.y;
  const int* h = hist + b*1024;
  int cb = sel[b*4+0];
  int acc0 = sel[b*4+1];
  int loc[16]; int s=0;
  #pragma unroll
  for (int j=0;j<16;j++){ loc[j]=h[lane*16+j]; s+=loc[j]; }
  int T=s;
  #pragma unroll
  for (int o=1;o<64;o<<=1){ int t=__shfl_down(T,o,64); if (lane+o<64) T+=t; }
  int S = acc0 + (T - s);
  int Ti = acc0 + T;
  if (S < K_SELECT && Ti >= K_SELECT){
    int acc=S;
    #pragma unroll
    for (int j=15;j>=0;j--){
      acc+=loc[j];
      if (acc>=K_SELECT){
        sel[b*4+2]=(cb<<10)|(lane*16+j);
        sel[b*4+3]=K_SELECT-(acc-loc[j]);
        break;
      }
    }
  }
}

__global__ __launch_bounds__(256) void k_mask_init(const int* __restrict__ smap, const int* __restrict__ sel,
                                                   float* __restrict__ mask, uint32_t* __restrict__ bits,
                                                   int* __restrict__ tiecnt, int* __restrict__ tielist){
  int idx = blockIdx.x*256+threadIdx.x;
  int b = idx>>18;
  int v = smap[idx];
  int T = sel[b*4+2];
  bool unk = (v>T);
  unsigned long long bal = __ballot(unk);
  if ((threadIdx.x&63)==0){
    bits[idx>>5]     = (uint32_t)(bal);
    bits[(idx>>5)+1] = (uint32_t)(bal>>32);
  }
  if (v==T){
    int t = atomicAdd(&tiecnt[b],1);
    if (t<CAP_TIES) tielist[b*CAP_TIES+t] = idx & (SPATIAL-1);
  }
  mask[idx]= unk? 0.f : 1.f;
}

__global__ __launch_bounds__(256) void k_tie_fix(const int* __restrict__ sel, const int* __restrict__ tiecnt,
                                                 const int* __restrict__ tielist, float* __restrict__ mask,
                                                 uint32_t* __restrict__ bits){
  int b=blockIdx.x;
  int n = tiecnt[b]; if (n>CAP_TIES) n=CAP_TIES;
  int need = sel[b*4+3];
  for (int e=threadIdx.x; e<n; e+=256){
    int me = tielist[b*CAP_TIES+e];
    int rank=0;
    for (int j=0;j<n;j++) rank += (tielist[b*CAP_TIES+j] < me) ? 1:0;
    if (rank<need){
      mask[b*SPATIAL+me]=0.f;
      atomicOr(&bits[(b<<13)+(me>>5)], 1u<<(me&31));
    }
  }
}

// ---------------- stencil helpers ----------------
__device__ __forceinline__ void bwin(const float v[8], float w[10], int lane){
  float up = __shfl_up(v[7],1,64);
  float dn = __shfl_down(v[0],1,64);
  w[0] = (lane==0)?0.f:up;
  #pragma unroll
  for(int e=0;e<8;e++) w[e+1]=v[e];
  w[9] = (lane==63)?0.f:dn;
}
__device__ __forceinline__ float accE(const float* wm, const float* wc, const float* wp, int e){
  const float WE=1.f/6.f, WC=1.f/12.f;
  return WE*(wm[e+1]+wp[e+1]+wc[e]+wc[e+2]) + WC*(wm[e]+wm[e+2]+wp[e]+wp[e+2]);
}
// masked variant for plane-crossing bands: um/up gate the above/below rows
__device__ __forceinline__ float accEm(const float* wm, const float* wc, const float* wp, int e, float um, float up){
  const float WE=1.f/6.f, WC=1.f/12.f;
  return WE*(um*wm[e+1]+up*wp[e+1]+wc[e]+wc[e+2]) + WC*(um*(wm[e]+wm[e+2])+up*(wp[e]+wp[e+2]));
}
__device__ __forceinline__ h16x8 loadg8(const h16* buf, int g, int x0){
  h16x8 t;
  if ((unsigned)g < (unsigned)GROWS){
    t = *(const h16x8*)(buf + (size_t)g*HW + x0);
  } else {
    #pragma unroll
    for (int e=0;e<8;e++) t[e]=(h16)0.f;
  }
  return t;
}
__device__ __forceinline__ void unpack8(const h16x8 t, float v[8]){
  #pragma unroll
  for (int e=0;e<8;e++) v[e]=(float)t[e];
}

// 3-dot (f32 in-wave) block reduce + f64 atomic emit
__device__ __forceinline__ void dots_emit(float a,float b,float c,int tid,double* dst,int it){
  #pragma unroll
  for (int o=32;o>0;o>>=1){ a+=__shfl_down(a,o,64); b+=__shfl_down(b,o,64); c+=__shfl_down(c,o,64); }
  __shared__ double s3[3][4];
  int wv = tid>>6;
  if ((tid&63)==0){ s3[0][wv]=(double)a; s3[1][wv]=(double)b; s3[2][wv]=(double)c; }
  __syncthreads();
  if (tid==0){
    double A=s3[0][0]+s3[0][1]+s3[0][2]+s3[0][3];
    double B=s3[1][0]+s3[1][1]+s3[1][2]+s3[1][3];
    double C=s3[2][0]+s3[2][1]+s3[2][2]+s3[2][3];
    int slot = blockIdx.x & (NSLOT-1);
    atomicAdd(&dst[(((size_t)it*3+0)*NSLOT+slot)*PAD], A);
    atomicAdd(&dst[(((size_t)it*3+1)*NSLOT+slot)*PAD], B);
    atomicAdd(&dst[(((size_t)it*3+2)*NSLOT+slot)*PAD], C);
  }
}

// sw = WE*(u+v) + WC*u*v with u = row-uniform, v = lane-const
#define SW_ROW(u) float t1_=(1.f/6.f)*(u), t2_=(1.f/6.f)+(1.f/12.f)*(u)
#define SW_E(e)   fmaf(t2_, vxe[e], t1_)

// ---------------- rhs: p0 (= r0) = unk*stencil(known*img); dots pAp0, ApAp0, rr0 ----------------
// Batch-loaded: all 8 img rows + 8 bits words staged up front (one latency exposure).
__global__ __launch_bounds__(256) void k_rhs(const float* __restrict__ img, const uint32_t* __restrict__ bits,
                                             h16* __restrict__ p0, double* __restrict__ dots){
  int lane=threadIdx.x; int tid=threadIdx.y*64+lane;
  int w = blockIdx.x*4+threadIdx.y;
  int plane = w>>7; int a = (w&127)*RBAND;
  const float* ip = img + (size_t)plane*SPATIAL;
  h16* rn = p0 + (size_t)plane*SPATIAL;
  const uint32_t* ub = bits + ((size_t)(plane/CH)<<13);
  int x0=lane*8, wofs=lane>>2, bit0=(lane&3)*8;
  float vxe[8];
  #pragma unroll
  for (int e=0;e<8;e++){
    int xg=x0+e;
    vxe[e] = ((xg>0)?1.f:0.f) + ((xg<HW-1)?1.f:0.f);
  }

  // stage rows a-2 .. a+RBAND+1
  f32x8 ivr[RBAND+4];
  uint32_t ubr2[RBAND+4];
  #pragma unroll
  for (int k=0;k<RBAND+4;k++){
    int y = a-2+k;
    if ((unsigned)y < HW){
      ivr[k] = *(const f32x8*)(ip + y*HW + x0);
      ubr2[k] = ub[y*16 + wofs];
    } else {
      f32x8 z;
      #pragma unroll
      for (int e=0;e<8;e++) z[e]=0.f;
      ivr[k]=z;
      ubr2[k]=0u;
    }
  }

  float wv_m[10], wv_c[10], wv_p[10], wr_2[10], wr_1[10], wr_0[10];
  float t[8];
  #pragma unroll
  for (int e=0;e<8;e++) t[e] = ((ubr2[0]>>(bit0+e))&1u)? 0.f : ivr[0][e];
  bwin(t,wv_m,lane);
  #pragma unroll
  for (int e=0;e<8;e++) t[e] = ((ubr2[1]>>(bit0+e))&1u)? 0.f : ivr[1][e];
  bwin(t,wv_c,lane);
  #pragma unroll
  for (int j=0;j<10;j++){ wr_2[j]=0.f; wr_1[j]=0.f; }
  float d_pap=0.f, d_apap=0.f, d_rr=0.f;
  #pragma unroll
  for (int j=0;j<RBAND+2;j++){
    int y = a-1+j;
    #pragma unroll
    for (int e=0;e<8;e++) t[e] = ((ubr2[j+2]>>(bit0+e))&1u)? 0.f : ivr[j+2][e];
    bwin(t,wv_p,lane);
    uint32_t uy = ubr2[j+1];
    float rr8[8];
    #pragma unroll
    for (int e=0;e<8;e++){
      float rv = ((uy>>(bit0+e))&1u)? accE(wv_m,wv_c,wv_p,e) : 0.f;
      rr8[e] = (float)(h16)rv;
    }
    if (j>=1 && j<1+RBAND){
      h16x8 rw;
      #pragma unroll
      for (int e=0;e<8;e++){ rw[e]=(h16)rr8[e]; d_rr = fmaf(rr8[e],rr8[e],d_rr); }
      *(h16x8*)(rn + y*HW + x0) = rw;
    }
    bwin(rr8, wr_0, lane);
    if (j>=2){
      int yc = y-1;
      float u = ((yc>0)?1.f:0.f) + ((yc<HW-1)?1.f:0.f);
      SW_ROW(u);
      uint32_t ubp = ubr2[j];
      #pragma unroll
      for (int e=0;e<8;e++){
        float unk = (float)((ubp>>(bit0+e))&1u);
        float Ap = unk * (SW_E(e)*wr_1[e+1] - accE(wr_2,wr_1,wr_0,e));
        d_pap = fmaf(wr_1[e+1],Ap,d_pap);
        d_apap= fmaf(Ap,Ap,d_apap);
      }
    }
    #pragma unroll
    for (int jj=0;jj<10;jj++){ wv_m[jj]=wv_c[jj]; wv_c[jj]=wv_p[jj]; wr_2[jj]=wr_1[jj]; wr_1[jj]=wr_0[jj]; }
  }
  dots_emit(d_pap,d_apap,d_rr,tid,dots,0);
}

// ---------------- merged CG iteration: global-row bands, r-free, deferred-x, batch-loaded ----------------
__global__ __launch_bounds__(256) void k_cg(const h16* __restrict__ pm1, const h16* __restrict__ pm2,
    h16* __restrict__ pn, h16* __restrict__ xv, const uint32_t* __restrict__ bits,
    double* __restrict__ dots, double* __restrict__ betas, double* __restrict__ alphas, int iter){
  int lane = threadIdx.x;
  int tid = threadIdx.y*64 + lane;
  int w = blockIdx.x*4 + threadIdx.y;
  int g0 = w * CBAND;
  int x0 = lane*8;
  int wofs = lane>>2;
  int bit0 = (lane&3)*8;

  // ---- batch-issue all row loads first (independent; overlap with dots reduce) ----
  h16x8 p1r[CBAND+4];            // global rows g0-2 .. g0+CBAND+1
  h16x8 p2r[CBAND+2];            // global rows g0-1 .. g0+CBAND
  uint32_t ubr[CBAND+2];
  #pragma unroll
  for (int k=0;k<CBAND+4;k++) p1r[k] = loadg8(pm1, g0-2+k, x0);
  if (iter>1){
    #pragma unroll
    for (int k=0;k<CBAND+2;k++) p2r[k] = loadg8(pm2, g0-1+k, x0);
  } else {
    #pragma unroll
    for (int k=0;k<CBAND+2;k++){
      h16x8 z;
      #pragma unroll
      for (int e=0;e<8;e++) z[e]=(h16)0.f;
      p2r[k]=z;
    }
  }
  #pragma unroll
  for (int k=0;k<CBAND+2;k++){
    int gy = g0-1+k;
    int py = gy & (HW-1);
    int bidx = (gy>>9)/CH;
    ubr[k] = ((unsigned)gy<(unsigned)GROWS)? bits[((size_t)bidx<<13)+py*16+wofs] : 0u;
  }

  __shared__ float sab[4];
  if (tid < 64){
    size_t bse = (((size_t)(iter-1)*3)*NSLOT + tid)*PAD;
    double pap = dots[bse];
    double apap= dots[bse + (size_t)NSLOT*PAD];
    double rr  = dots[bse + (size_t)2*NSLOT*PAD];
    #pragma unroll
    for (int o=32;o>0;o>>=1){ pap+=__shfl_down(pap,o,64); apap+=__shfl_down(apap,o,64); rr+=__shfl_down(rr,o,64); }
    if (tid==0){
      double al = (pap!=0.0)? rr/pap : 0.0;
      double rrn = al*al*apap - rr;
      double bi = (rr!=0.0)? rrn/rr : 0.0;
      double bp = (iter>=2)? betas[iter-1] : 0.0;
      double ap_= (iter>=2)? alphas[iter-1] : 0.0;
      sab[0]=(float)al; sab[1]=(float)bp; sab[2]=(float)bi; sab[3]=(float)ap_;
      if (blockIdx.x==0){ betas[iter]=bi; alphas[iter]=al; }
    }
  }
  __syncthreads();
  float alpha=sab[0], bprev=sab[1], bnext=sab[2], aprev=sab[3];
  int do_x = ((iter&1)==0);

  float vxe[8];
  #pragma unroll
  for (int e=0;e<8;e++){
    int xg=x0+e;
    vxe[e] = ((xg>0)?1.f:0.f) + ((xg<HW-1)?1.f:0.f);
  }

  float w1m[10], w1c[10], w1p[10];
  float wi2[10], wi1[10], wi0[10];
  float t[8];
  unpack8(p1r[0], t); bwin(t, w1m, lane);
  unpack8(p1r[1], t); bwin(t, w1c, lane);
  #pragma unroll
  for (int j=0;j<10;j++){ wi2[j]=0.f; wi1[j]=0.f; }
  uint32_t ub_1 = 0;
  float d_pap=0.f, d_apap=0.f, d_rr=0.f;
  #pragma unroll
  for (int j=0;j<CBAND+2;j++){
    int gy = g0-1+j;
    int py = gy & (HW-1);
    unpack8(p1r[j+2], t); bwin(t, w1p, lane);
    float r2[8]; unpack8(p2r[j], r2);
    uint32_t uy = ubr[j];
    float um = (py>0)?1.f:0.f, up = (py<HW-1)?1.f:0.f;
    float u = um+up;
    SW_ROW(u);
    float rv8[8], pi[8];
    #pragma unroll
    for (int e=0;e<8;e++){
      float unk = (float)((uy>>(bit0+e))&1u);
      float Ap = unk * (SW_E(e)*w1c[e+1] - accEm(w1m,w1c,w1p,e,um,up));
      float rt = w1c[e+1] - bprev*r2[e];     // reconstructed r_{i-1}
      float rv = rt - alpha*Ap;
      rv = (float)(h16)rv;
      float pv = rv + bnext*w1c[e+1];
      pv = (float)(h16)pv;
      rv8[e]=rv; pi[e]=pv;
    }
    if (j>=1 && j<1+CBAND){
      h16x8 pw;
      #pragma unroll
      for (int e=0;e<8;e++){
        pw[e] = (h16)pi[e];
        d_rr = fmaf(rv8[e],rv8[e],d_rr);
      }
      if (do_x){
        h16x8 xo;
        if (iter==2){
          #pragma unroll
          for (int e=0;e<8;e++)
            xo[e] = (h16)(alpha*w1c[e+1] + aprev*r2[e]);   // x was 0
        } else {
          h16x8 xc = *(const h16x8*)(xv + (size_t)gy*HW + x0);
          #pragma unroll
          for (int e=0;e<8;e++)
            xo[e] = (h16)((float)xc[e] + alpha*w1c[e+1] + aprev*r2[e]);
        }
        *(h16x8*)(xv + (size_t)gy*HW + x0) = xo;
      }
      *(h16x8*)(pn + (size_t)gy*HW + x0) = pw;
    }
    bwin(pi, wi0, lane);
    if (j>=2){
      int gc = gy-1;
      int pyc = gc & (HW-1);
      float umc = (pyc>0)?1.f:0.f, upc = (pyc<HW-1)?1.f:0.f;
      float u2 = umc+upc;
      float t1b=(1.f/6.f)*u2, t2b=(1.f/6.f)+(1.f/12.f)*u2;
      #pragma unroll
      for (int e=0;e<8;e++){
        float unk = (float)((ub_1>>(bit0+e))&1u);
        float Ap = unk * (fmaf(t2b,vxe[e],t1b)*wi1[e+1] - accEm(wi2,wi1,wi0,e,umc,upc));
        d_pap = fmaf(wi1[e+1],Ap,d_pap);
        d_apap= fmaf(Ap,Ap,d_apap);
      }
    }
    #pragma unroll
    for (int jj=0;jj<10;jj++){ w1m[jj]=w1c[jj]; w1c[jj]=w1p[jj]; wi2[jj]=wi1[jj]; wi1[jj]=wi0[jj]; }
    ub_1 = uy;
  }
  dots_emit(d_pap,d_apap,d_rr,tid,dots,iter);
}

// ---------------- fused final: x_N = x + a_N*p_{N-1} + a_{N-1}*p_{N-2}; compose out ----------------
__global__ __launch_bounds__(256) void k_final2(const float* __restrict__ img, const float* __restrict__ noise,
    const uint32_t* __restrict__ bits, const h16* __restrict__ xv,
    const h16* __restrict__ pm1, const h16* __restrict__ pm2,
    const double* __restrict__ dots, const double* __restrict__ alphas, float* __restrict__ out){
  int lane = threadIdx.x;
  int tid = threadIdx.y*64 + lane;
  __shared__ float sab[2];
  if (tid < 64){
    size_t bse = (((size_t)(NITER-1)*3)*NSLOT + tid)*PAD;
    double pap = dots[bse];
    double rr  = dots[bse + (size_t)2*NSLOT*PAD];
    #pragma unroll
    for (int o=32;o>0;o>>=1){ pap+=__shfl_down(pap,o,64); rr+=__shfl_down(rr,o,64); }
    if (tid==0){
      sab[0] = (pap!=0.0)? (float)(rr/pap) : 0.f;   // alpha_N
      sab[1] = (float)alphas[NITER-1];              // alpha_{N-1}
    }
  }
  __syncthreads();
  float alpha=sab[0], aprev=sab[1];

  int y = blockIdx.x*4 + threadIdx.y;
  int bc = blockIdx.y;
  size_t base = (size_t)bc*SPATIAL;
  int x0 = lane*8;
  int sp0 = y*HW + x0;
  const uint32_t* ub = bits + ((size_t)(bc/CH)<<13);
  f32x8 iv = *(const f32x8*)(img+base+sp0);
  f32x8 nv = *(const f32x8*)(noise+base+sp0);
  h16x8 xc = *(const h16x8*)(xv+base+sp0);
  h16x8 p1 = *(const h16x8*)(pm1+base+sp0);
  h16x8 p2 = *(const h16x8*)(pm2+base+sp0);
  uint32_t wb = ub[y*16 + (lane>>2)];
  int bit0 = (lane&3)*8;
  f32x8 ov;
  #pragma unroll
  for (int e=0;e<8;e++){
    float xn = (float)xc[e] + alpha*(float)p1[e] + aprev*(float)p2[e];
    ov[e] = ((wb>>(bit0+e))&1u) ? (xn + 0.01f*nv[e]) : iv[e];
  }
  *(f32x8*)(out+base+sp0) = ov;
}

extern "C" void kernel_launch(void* const* d_in, const int* in_sizes, int n_in,
                              void* d_out, int out_size, void* d_ws, size_t ws_size,
                              hipStream_t stream) {
  const float* img  =(const float*)d_in[0];
  const int*   smap =(const int*)d_in[1];
  const float* noise=(const float*)d_in[2];
  float* out=(float*)d_out;
  float* maskout = out + NELEM;          // mask output region (B,H,W)
  char* ws=(char*)d_ws;
  h16* pbuf[3] = { (h16*)(ws+OFF_P0), (h16*)(ws+OFF_P1), (h16*)(ws+OFF_P2) };
  h16* xv =(h16*)(ws+OFF_X);
  uint32_t* bits=(uint32_t*)(ws+OFF_BITS);
  double* dots=(double*)(ws+OFF_DOTS);
  double* betas=(double*)(ws+OFF_BETA);
  double* alphas=(double*)(ws+OFF_ALPH);
  int* hc=(int*)(ws+OFF_HC);
  int* hf=(int*)(ws+OFF_HF);
  int* sel=(int*)(ws+OFF_SEL);
  int* tiecnt=(int*)(ws+OFF_TC);
  int* tielist=(int*)(ws+OFF_TL);

  // zero dots, betas/alphas, hists, sel, tiecnt (x written by iter-2 do_x; bits fully overwritten)
  hipMemsetAsync(ws+OFF_DOTS, 0, OFF_TL-OFF_DOTS, stream);

  // mask pipeline
  k_hist_coarse<<<dim3(64,16),256,0,stream>>>(smap,hc);
  k_select_coarse<<<1,dim3(64,16),0,stream>>>(hc,sel);
  k_hist_fine<<<dim3(64,16),256,0,stream>>>(smap,sel,hf);
  k_select_fine<<<1,dim3(64,16),0,stream>>>(hf,sel);
  k_mask_init<<<SPATIAL*BATCH/256,256,0,stream>>>(smap,sel,maskout,bits,tiecnt,tielist);
  k_tie_fix<<<16,256,0,stream>>>(sel,tiecnt,tielist,maskout,bits);

  // rhs -> p0 (plane-local bands, RBAND=4, batch-loaded)
  dim3 grhs(NPLANE*(HW/RBAND)/4), brhs(64,4);
  k_rhs<<<grhs,brhs,0,stream>>>(img,bits,pbuf[0],dots);

  // CG: iterations 1..NITER-1 (1024 blocks x (64,4) = 4096 waves = one residency round)
  dim3 gcg(GROWS/CBAND/4), bcg(64,4);
  for (int i=1;i<=NITER-1;i++){
    const h16* pm1 = pbuf[(i-1)%3];
    const h16* pm2 = (i>=2)? pbuf[(i-2)%3] : pbuf[0];   // i==1: bprev=aprev=0, pm2 unused but finite
    h16* pn        = pbuf[i%3];
    k_cg<<<gcg,bcg,0,stream>>>(pm1,pm2,pn,xv,bits,dots,betas,alphas,i);
  }

  // fused last iteration + compose
  {
    const h16* pm1 = pbuf[(NITER-1)%3];
    const h16* pm2 = pbuf[(NITER-2)%3];
    k_final2<<<dim3(HW/4,NPLANE),bcg,0,stream>>>(img,noise,bits,xv,pm1,pm2,dots,alphas,out);
  }
}

// Round 15
// 321.584 us; speedup vs baseline: 1.1649x; 1.1649x over previous
//
#include <hip/hip_runtime.h>
#include <cstdint>
#include <cstddef>

#define HW 512
#define SPATIAL (HW*HW)              // 262144
#define BATCH 16
#define CH 3
#define NPLANE (BATCH*CH)            // 48
#define NELEM ((size_t)NPLANE*SPATIAL) // 12582912
#define GROWS (NPLANE*HW)            // 24576 global rows
#define K_SELECT 78643
#define NITER 8
#define CAP_TIES 4096
#define NSLOT 64
#define PAD 8     // doubles per slot -> one 64B line per slot
#define RBAND 4   // rows per wave in k_rhs (plane-local)
#define CBAND 6   // global rows per wave in k_cg -> 4096 waves = 1 residency round

typedef _Float16 h16;
typedef __attribute__((ext_vector_type(8))) _Float16 h16x8;  // 16B
typedef __attribute__((ext_vector_type(8))) float f32x8;     // 32B

// workspace layout: 3 rotating p buffers, x, bits, dots, betas/alphas, hists
static const size_t OFF_P0   = 0;                      // h16[NELEM]
static const size_t OFF_P1   = NELEM*2;                // h16[NELEM]
static const size_t OFF_P2   = NELEM*4;                // h16[NELEM]
static const size_t OFF_BITS = NELEM*6;                // uint32[BATCH*8192] = 512KB (fully written)
static const size_t OFF_X    = OFF_BITS + (size_t)BATCH*8192*4;   // h16[NELEM] (written by iter-2 do_x, no memset)
static const size_t OFF_DOTS = OFF_X + NELEM*2;        // double[(NITER+1)*3*NSLOT*PAD]  <- memset starts here
static const size_t OFF_BETA = OFF_DOTS + (size_t)(NITER+1)*3*NSLOT*PAD*8;  // double[NITER+1]
static const size_t OFF_ALPH = OFF_BETA + (size_t)(NITER+1)*8;              // double[NITER+1]
static const size_t OFF_HC   = OFF_ALPH + (size_t)(NITER+1)*8;
static const size_t OFF_HF   = OFF_HC + (size_t)BATCH*1024*4;
static const size_t OFF_SEL  = OFF_HF + (size_t)BATCH*1024*4;     // int[16][4]
static const size_t OFF_TC   = OFF_SEL + (size_t)BATCH*4*4;       // int[16]
static const size_t OFF_TL   = OFF_TC + 64;                       // int[16][CAP_TIES]

// ---------------- mask pipeline ----------------
__global__ __launch_bounds__(256) void k_hist_coarse(const int* __restrict__ smap, int* __restrict__ hist){
  __shared__ int h[1024];
  int tid = threadIdx.x;
  for (int j=tid;j<1024;j+=256) h[j]=0;
  __syncthreads();
  int b = blockIdx.y;
  int base = b*SPATIAL + blockIdx.x*4096;
  #pragma unroll
  for (int e=0;e<16;e++){
    int v = smap[base + e*256 + tid];
    atomicAdd(&h[v>>10], 1);
  }
  __syncthreads();
  for (int j=tid;j<1024;j+=256){ int c=h[j]; if(c) atomicAdd(&hist[b*1024+j], c); }
}

__global__ __launch_bounds__(1024) void k_select_coarse(const int* __restrict__ hist, int* __restrict__ sel){
  int lane = threadIdx.x, b = threadIdx.y;
  const int* h = hist + b*1024;
  int loc[16]; int s=0;
  #pragma unroll
  for (int j=0;j<16;j++){ loc[j]=h[lane*16+j]; s+=loc[j]; }
  int T=s;
  #pragma unroll
  for (int o=1;o<64;o<<=1){ int t=__shfl_down(T,o,64); if (lane+o<64) T+=t; }
  int S = T - s;
  if (S < K_SELECT && T >= K_SELECT){
    int acc=S;
    #pragma unroll
    for (int j=15;j>=0;j--){
      acc+=loc[j];
      if (acc>=K_SELECT){ sel[b*4+0]=lane*16+j; sel[b*4+1]=acc-loc[j]; break; }
    }
  }
}

__global__ __launch_bounds__(256) void k_hist_fine(const int* __restrict__ smap, const int* __restrict__ sel, int* __restrict__ hist){
  __shared__ int h[1024];
  int tid=threadIdx.x;
  for (int j=tid;j<1024;j+=256) h[j]=0;
  __syncthreads();
  int b=blockIdx.y;
  int cb = sel[b*4+0];
  int base = b*SPATIAL + blockIdx.x*4096;
  #pragma unroll
  for (int e=0;e<16;e++){
    int v = smap[base+e*256+tid];
    if ((v>>10)==cb) atomicAdd(&h[v&1023],1);
  }
  __syncthreads();
  for (int j=tid;j<1024;j+=256){ int c=h[j]; if(c) atomicAdd(&hist[b*1024+j],c); }
}

__global__ __launch_bounds__(1024) void k_select_fine(const int* __restrict__ hist, int* __restrict__ sel){
  int lane = threadIdx.x, b = threadIdx.y;
  const int* h = hist + b*1024;
  int cb = sel[b*4+0];
  int acc0 = sel[b*4+1];
  int loc[16]; int s=0;
  #pragma unroll
  for (int j=0;j<16;j++){ loc[j]=h[lane*16+j]; s+=loc[j]; }
  int T=s;
  #pragma unroll
  for (int o=1;o<64;o<<=1){ int t=__shfl_down(T,o,64); if (lane+o<64) T+=t; }
  int S = acc0 + (T - s);
  int Ti = acc0 + T;
  if (S < K_SELECT && Ti >= K_SELECT){
    int acc=S;
    #pragma unroll
    for (int j=15;j>=0;j--){
      acc+=loc[j];
      if (acc>=K_SELECT){
        sel[b*4+2]=(cb<<10)|(lane*16+j);
        sel[b*4+3]=K_SELECT-(acc-loc[j]);
        break;
      }
    }
  }
}

__global__ __launch_bounds__(256) void k_mask_init(const int* __restrict__ smap, const int* __restrict__ sel,
                                                   float* __restrict__ mask, uint32_t* __restrict__ bits,
                                                   int* __restrict__ tiecnt, int* __restrict__ tielist){
  int idx = blockIdx.x*256+threadIdx.x;
  int b = idx>>18;
  int v = smap[idx];
  int T = sel[b*4+2];
  bool unk = (v>T);
  unsigned long long bal = __ballot(unk);
  if ((threadIdx.x&63)==0){
    bits[idx>>5]     = (uint32_t)(bal);
    bits[(idx>>5)+1] = (uint32_t)(bal>>32);
  }
  if (v==T){
    int t = atomicAdd(&tiecnt[b],1);
    if (t<CAP_TIES) tielist[b*CAP_TIES+t] = idx & (SPATIAL-1);
  }
  mask[idx]= unk? 0.f : 1.f;
}

__global__ __launch_bounds__(256) void k_tie_fix(const int* __restrict__ sel, const int* __restrict__ tiecnt,
                                                 const int* __restrict__ tielist, float* __restrict__ mask,
                                                 uint32_t* __restrict__ bits){
  int b=blockIdx.x;
  int n = tiecnt[b]; if (n>CAP_TIES) n=CAP_TIES;
  int need = sel[b*4+3];
  for (int e=threadIdx.x; e<n; e+=256){
    int me = tielist[b*CAP_TIES+e];
    int rank=0;
    for (int j=0;j<n;j++) rank += (tielist[b*CAP_TIES+j] < me) ? 1:0;
    if (rank<need){
      mask[b*SPATIAL+me]=0.f;
      atomicOr(&bits[(b<<13)+(me>>5)], 1u<<(me&31));
    }
  }
}

// ---------------- stencil helpers ----------------
__device__ __forceinline__ void bwin(const float v[8], float w[10], int lane){
  float up = __shfl_up(v[7],1,64);
  float dn = __shfl_down(v[0],1,64);
  w[0] = (lane==0)?0.f:up;
  #pragma unroll
  for(int e=0;e<8;e++) w[e+1]=v[e];
  w[9] = (lane==63)?0.f:dn;
}
__device__ __forceinline__ float accE(const float* wm, const float* wc, const float* wp, int e){
  const float WE=1.f/6.f, WC=1.f/12.f;
  return WE*(wm[e+1]+wp[e+1]+wc[e]+wc[e+2]) + WC*(wm[e]+wm[e+2]+wp[e]+wp[e+2]);
}
// masked variant for plane-crossing bands: um/up gate the above/below rows
__device__ __forceinline__ float accEm(const float* wm, const float* wc, const float* wp, int e, float um, float up){
  const float WE=1.f/6.f, WC=1.f/12.f;
  return WE*(um*wm[e+1]+up*wp[e+1]+wc[e]+wc[e+2]) + WC*(um*(wm[e]+wm[e+2])+up*(wp[e]+wp[e+2]));
}
__device__ __forceinline__ h16x8 loadg8(const h16* buf, int g, int x0){
  h16x8 t;
  if ((unsigned)g < (unsigned)GROWS){
    t = *(const h16x8*)(buf + (size_t)g*HW + x0);
  } else {
    #pragma unroll
    for (int e=0;e<8;e++) t[e]=(h16)0.f;
  }
  return t;
}
__device__ __forceinline__ void unpack8(const h16x8 t, float v[8]){
  #pragma unroll
  for (int e=0;e<8;e++) v[e]=(float)t[e];
}

// 3-dot (f32 in-wave) block reduce + f64 atomic emit
__device__ __forceinline__ void dots_emit(float a,float b,float c,int tid,double* dst,int it){
  #pragma unroll
  for (int o=32;o>0;o>>=1){ a+=__shfl_down(a,o,64); b+=__shfl_down(b,o,64); c+=__shfl_down(c,o,64); }
  __shared__ double s3[3][4];
  int wv = tid>>6;
  if ((tid&63)==0){ s3[0][wv]=(double)a; s3[1][wv]=(double)b; s3[2][wv]=(double)c; }
  __syncthreads();
  if (tid==0){
    double A=s3[0][0]+s3[0][1]+s3[0][2]+s3[0][3];
    double B=s3[1][0]+s3[1][1]+s3[1][2]+s3[1][3];
    double C=s3[2][0]+s3[2][1]+s3[2][2]+s3[2][3];
    int slot = blockIdx.x & (NSLOT-1);
    atomicAdd(&dst[(((size_t)it*3+0)*NSLOT+slot)*PAD], A);
    atomicAdd(&dst[(((size_t)it*3+1)*NSLOT+slot)*PAD], B);
    atomicAdd(&dst[(((size_t)it*3+2)*NSLOT+slot)*PAD], C);
  }
}

// sw = WE*(u+v) + WC*u*v with u = row-uniform, v = lane-const
#define SW_ROW(u) float t1_=(1.f/6.f)*(u), t2_=(1.f/6.f)+(1.f/12.f)*(u)
#define SW_E(e)   fmaf(t2_, vxe[e], t1_)

// ---------------- rhs: p0 (= r0) = unk*stencil(known*img); dots pAp0, ApAp0, rr0 ----------------
__global__ __launch_bounds__(256) void k_rhs(const float* __restrict__ img, const uint32_t* __restrict__ bits,
                                             h16* __restrict__ p0, double* __restrict__ dots){
  int lane=threadIdx.x; int tid=threadIdx.y*64+lane;
  int w = blockIdx.x*4+threadIdx.y;
  int plane = w>>7; int a = (w&127)*RBAND;
  const float* ip = img + (size_t)plane*SPATIAL;
  h16* rn = p0 + (size_t)plane*SPATIAL;
  const uint32_t* ub = bits + ((size_t)(plane/CH)<<13);
  int x0=lane*8, wofs=lane>>2, bit0=(lane&3)*8;
  float vxe[8];
  #pragma unroll
  for (int e=0;e<8;e++){
    int xg=x0+e;
    vxe[e] = ((xg>0)?1.f:0.f) + ((xg<HW-1)?1.f:0.f);
  }
  float wv_m[10], wv_c[10], wv_p[10], wr_2[10], wr_1[10], wr_0[10];
  float t[8];
  auto loadv=[&](int y, float v[8]){
    if ((unsigned)y < HW){
      f32x8 iv = *(const f32x8*)(ip + y*HW + x0);
      uint32_t uy = ub[y*16 + wofs];
      #pragma unroll
      for (int e=0;e<8;e++) v[e] = ((uy>>(bit0+e))&1u)? 0.f : iv[e];
    } else {
      #pragma unroll
      for (int e=0;e<8;e++) v[e]=0.f;
    }
  };
  loadv(a-2,t); bwin(t,wv_m,lane);
  loadv(a-1,t); bwin(t,wv_c,lane);
  #pragma unroll
  for (int j=0;j<10;j++){ wr_2[j]=0.f; wr_1[j]=0.f; }
  uint32_t ub_1=0;
  float d_pap=0.f, d_apap=0.f, d_rr=0.f;
  #pragma unroll
  for (int j=0;j<RBAND+2;j++){
    int y = a-1+j;
    loadv(y+1,t); bwin(t,wv_p,lane);
    uint32_t uy = ((unsigned)y<HW)? ub[y*16+wofs] : 0u;
    float rr8[8];
    #pragma unroll
    for (int e=0;e<8;e++){
      float rv = ((uy>>(bit0+e))&1u)? accE(wv_m,wv_c,wv_p,e) : 0.f;
      rr8[e] = (float)(h16)rv;
    }
    if (j>=1 && j<1+RBAND){
      h16x8 rw;
      #pragma unroll
      for (int e=0;e<8;e++){ rw[e]=(h16)rr8[e]; d_rr = fmaf(rr8[e],rr8[e],d_rr); }
      *(h16x8*)(rn + y*HW + x0) = rw;
    }
    bwin(rr8, wr_0, lane);
    if (j>=2){
      int yc = y-1;
      float u = ((yc>0)?1.f:0.f) + ((yc<HW-1)?1.f:0.f);
      SW_ROW(u);
      #pragma unroll
      for (int e=0;e<8;e++){
        float unk = (float)((ub_1>>(bit0+e))&1u);
        float Ap = unk * (SW_E(e)*wr_1[e+1] - accE(wr_2,wr_1,wr_0,e));
        d_pap = fmaf(wr_1[e+1],Ap,d_pap);
        d_apap= fmaf(Ap,Ap,d_apap);
      }
    }
    #pragma unroll
    for (int jj=0;jj<10;jj++){ wv_m[jj]=wv_c[jj]; wv_c[jj]=wv_p[jj]; wr_2[jj]=wr_1[jj]; wr_1[jj]=wr_0[jj]; }
    ub_1 = uy;
  }
  dots_emit(d_pap,d_apap,d_rr,tid,dots,0);
}

// ---------------- merged CG iteration: global-row bands, r-free, deferred-x, batch-loaded ----------------
// Wave w in [0,4096) owns global rows [w*CBAND, (w+1)*CBAND); bands may cross plane
// boundaries; per-row um/up masks gate cross-plane window contributions.
__global__ __launch_bounds__(256) void k_cg(const h16* __restrict__ pm1, const h16* __restrict__ pm2,
    h16* __restrict__ pn, h16* __restrict__ xv, const uint32_t* __restrict__ bits,
    double* __restrict__ dots, double* __restrict__ betas, double* __restrict__ alphas, int iter, int last){
  int lane = threadIdx.x;
  int tid = threadIdx.y*64 + lane;
  int w = blockIdx.x*4 + threadIdx.y;
  int g0 = w * CBAND;
  int x0 = lane*8;
  int wofs = lane>>2;
  int bit0 = (lane&3)*8;

  // ---- batch-issue all row loads first (independent; overlap with dots reduce) ----
  h16x8 p1r[CBAND+4];            // global rows g0-2 .. g0+CBAND+1
  h16x8 p2r[CBAND+2];            // global rows g0-1 .. g0+CBAND
  uint32_t ubr[CBAND+2];
  #pragma unroll
  for (int k=0;k<CBAND+4;k++) p1r[k] = loadg8(pm1, g0-2+k, x0);
  if (iter>1){
    #pragma unroll
    for (int k=0;k<CBAND+2;k++) p2r[k] = loadg8(pm2, g0-1+k, x0);
  } else {
    #pragma unroll
    for (int k=0;k<CBAND+2;k++){
      h16x8 z;
      #pragma unroll
      for (int e=0;e<8;e++) z[e]=(h16)0.f;
      p2r[k]=z;
    }
  }
  #pragma unroll
  for (int k=0;k<CBAND+2;k++){
    int gy = g0-1+k;
    int py = gy & (HW-1);
    int bidx = (gy>>9)/CH;
    ubr[k] = ((unsigned)gy<(unsigned)GROWS)? bits[((size_t)bidx<<13)+py*16+wofs] : 0u;
  }

  __shared__ float sab[4];
  if (tid < 64){
    size_t bse = (((size_t)(iter-1)*3)*NSLOT + tid)*PAD;
    double pap = dots[bse];
    double apap= dots[bse + (size_t)NSLOT*PAD];
    double rr  = dots[bse + (size_t)2*NSLOT*PAD];
    #pragma unroll
    for (int o=32;o>0;o>>=1){ pap+=__shfl_down(pap,o,64); apap+=__shfl_down(apap,o,64); rr+=__shfl_down(rr,o,64); }
    if (tid==0){
      double al = (pap!=0.0)? rr/pap : 0.0;
      double rrn = al*al*apap - rr;
      double bi = (rr!=0.0)? rrn/rr : 0.0;
      double bp = (iter>=2)? betas[iter-1] : 0.0;
      double ap_= (iter>=2)? alphas[iter-1] : 0.0;
      sab[0]=(float)al; sab[1]=(float)bp; sab[2]=(float)bi; sab[3]=(float)ap_;
      if (blockIdx.x==0){ betas[iter]=bi; alphas[iter]=al; }
    }
  }
  __syncthreads();
  float alpha=sab[0], bprev=sab[1], bnext=sab[2], aprev=sab[3];
  int do_x = ((iter&1)==0) || last;

  float vxe[8];
  #pragma unroll
  for (int e=0;e<8;e++){
    int xg=x0+e;
    vxe[e] = ((xg>0)?1.f:0.f) + ((xg<HW-1)?1.f:0.f);
  }

  float w1m[10], w1c[10], w1p[10];
  float wi2[10], wi1[10], wi0[10];
  float t[8];
  unpack8(p1r[0], t); bwin(t, w1m, lane);
  unpack8(p1r[1], t); bwin(t, w1c, lane);
  #pragma unroll
  for (int j=0;j<10;j++){ wi2[j]=0.f; wi1[j]=0.f; }
  uint32_t ub_1 = 0;
  float d_pap=0.f, d_apap=0.f, d_rr=0.f;
  #pragma unroll
  for (int j=0;j<CBAND+2;j++){
    int gy = g0-1+j;
    int py = gy & (HW-1);
    unpack8(p1r[j+2], t); bwin(t, w1p, lane);
    float r2[8]; unpack8(p2r[j], r2);
    uint32_t uy = ubr[j];
    float um = (py>0)?1.f:0.f, up = (py<HW-1)?1.f:0.f;
    float u = um+up;
    SW_ROW(u);
    float rv8[8], pi[8];
    #pragma unroll
    for (int e=0;e<8;e++){
      float unk = (float)((uy>>(bit0+e))&1u);
      float Ap = unk * (SW_E(e)*w1c[e+1] - accEm(w1m,w1c,w1p,e,um,up));
      float rt = w1c[e+1] - bprev*r2[e];     // reconstructed r_{i-1}
      float rv = rt - alpha*Ap;
      rv = (float)(h16)rv;
      float pv = rv + bnext*w1c[e+1];
      pv = (float)(h16)pv;
      rv8[e]=rv; pi[e]=pv;
    }
    if (j>=1 && j<1+CBAND){
      h16x8 pw;
      #pragma unroll
      for (int e=0;e<8;e++){
        pw[e] = (h16)pi[e];
        d_rr = fmaf(rv8[e],rv8[e],d_rr);
      }
      if (do_x){
        h16x8 xo;
        if (iter==2){
          #pragma unroll
          for (int e=0;e<8;e++)
            xo[e] = (h16)(alpha*w1c[e+1] + aprev*r2[e]);   // x was 0
        } else {
          h16x8 xc = *(const h16x8*)(xv + (size_t)gy*HW + x0);
          #pragma unroll
          for (int e=0;e<8;e++)
            xo[e] = (h16)((float)xc[e] + alpha*w1c[e+1] + aprev*r2[e]);
        }
        *(h16x8*)(xv + (size_t)gy*HW + x0) = xo;
      }
      if (!last) *(h16x8*)(pn + (size_t)gy*HW + x0) = pw;
    }
    bwin(pi, wi0, lane);
    if (!last && j>=2){
      int gc = gy-1;
      int pyc = gc & (HW-1);
      float umc = (pyc>0)?1.f:0.f, upc = (pyc<HW-1)?1.f:0.f;
      float u2 = umc+upc;
      float t1b=(1.f/6.f)*u2, t2b=(1.f/6.f)+(1.f/12.f)*u2;
      #pragma unroll
      for (int e=0;e<8;e++){
        float unk = (float)((ub_1>>(bit0+e))&1u);
        float Ap = unk * (fmaf(t2b,vxe[e],t1b)*wi1[e+1] - accEm(wi2,wi1,wi0,e,umc,upc));
        d_pap = fmaf(wi1[e+1],Ap,d_pap);
        d_apap= fmaf(Ap,Ap,d_apap);
      }
    }
    #pragma unroll
    for (int jj=0;jj<10;jj++){ w1m[jj]=w1c[jj]; w1c[jj]=w1p[jj]; wi2[jj]=wi1[jj]; wi1[jj]=wi0[jj]; }
    ub_1 = uy;
  }
  if (!last) dots_emit(d_pap,d_apap,d_rr,tid,dots,iter);
}

__global__ __launch_bounds__(256) void k_final(const float* __restrict__ img, const float* __restrict__ noise,
    const uint32_t* __restrict__ bits, const h16* __restrict__ xv, float* __restrict__ out){
  int lane = threadIdx.x;
  int y = blockIdx.x*4 + threadIdx.y;
  int bc = blockIdx.y;
  size_t base = (size_t)bc*SPATIAL;
  int x0 = lane*8;
  int sp0 = y*HW + x0;
  const uint32_t* ub = bits + ((size_t)(bc/CH)<<13);
  f32x8 iv = *(const f32x8*)(img+base+sp0);
  f32x8 nv = *(const f32x8*)(noise+base+sp0);
  h16x8 xc = *(const h16x8*)(xv+base+sp0);
  uint32_t wb = ub[y*16 + (lane>>2)];
  int bit0 = (lane&3)*8;
  f32x8 ov;
  #pragma unroll
  for (int e=0;e<8;e++){
    ov[e] = ((wb>>(bit0+e))&1u) ? ((float)xc[e] + 0.01f*nv[e]) : iv[e];
  }
  *(f32x8*)(out+base+sp0) = ov;
}

extern "C" void kernel_launch(void* const* d_in, const int* in_sizes, int n_in,
                              void* d_out, int out_size, void* d_ws, size_t ws_size,
                              hipStream_t stream) {
  const float* img  =(const float*)d_in[0];
  const int*   smap =(const int*)d_in[1];
  const float* noise=(const float*)d_in[2];
  float* out=(float*)d_out;
  float* maskout = out + NELEM;          // mask output region (B,H,W)
  char* ws=(char*)d_ws;
  h16* pbuf[3] = { (h16*)(ws+OFF_P0), (h16*)(ws+OFF_P1), (h16*)(ws+OFF_P2) };
  h16* xv =(h16*)(ws+OFF_X);
  uint32_t* bits=(uint32_t*)(ws+OFF_BITS);
  double* dots=(double*)(ws+OFF_DOTS);
  double* betas=(double*)(ws+OFF_BETA);
  double* alphas=(double*)(ws+OFF_ALPH);
  int* hc=(int*)(ws+OFF_HC);
  int* hf=(int*)(ws+OFF_HF);
  int* sel=(int*)(ws+OFF_SEL);
  int* tiecnt=(int*)(ws+OFF_TC);
  int* tielist=(int*)(ws+OFF_TL);

  // zero dots, betas/alphas, hists, sel, tiecnt (x written by iter-2 do_x; bits fully overwritten)
  hipMemsetAsync(ws+OFF_DOTS, 0, OFF_TL-OFF_DOTS, stream);

  // mask pipeline
  k_hist_coarse<<<dim3(64,16),256,0,stream>>>(smap,hc);
  k_select_coarse<<<1,dim3(64,16),0,stream>>>(hc,sel);
  k_hist_fine<<<dim3(64,16),256,0,stream>>>(smap,sel,hf);
  k_select_fine<<<1,dim3(64,16),0,stream>>>(hf,sel);
  k_mask_init<<<SPATIAL*BATCH/256,256,0,stream>>>(smap,sel,maskout,bits,tiecnt,tielist);
  k_tie_fix<<<16,256,0,stream>>>(sel,tiecnt,tielist,maskout,bits);

  // rhs -> p0 (plane-local bands, RBAND=4)
  dim3 grhs(NPLANE*(HW/RBAND)/4), brhs(64,4);
  k_rhs<<<grhs,brhs,0,stream>>>(img,bits,pbuf[0],dots);

  // CG: 1024 blocks x (64,4) = 4096 waves = exactly one residency round
  dim3 gcg(GROWS/CBAND/4), bcg(64,4);
  for (int i=1;i<=NITER;i++){
    const h16* pm1 = pbuf[(i-1)%3];
    const h16* pm2 = (i>=2)? pbuf[(i-2)%3] : pbuf[0];   // i==1: bprev=aprev=0, pm2 unused but finite
    h16* pn        = pbuf[i%3];
    k_cg<<<gcg,bcg,0,stream>>>(pm1,pm2,pn,xv,bits,dots,betas,alphas,i,(i==NITER)?1:0);
  }

  k_final<<<dim3(HW/4,NPLANE),bcg,0,stream>>>(img,noise,bits,xv,out);
}